// Round 12
// baseline (146.679 us; speedup 1.0000x reference)
//
#include <hip/hip_runtime.h>
#include <hip/hip_fp16.h>
#include <math.h>

// ---------------- problem constants ----------------
#define NB    256
#define NTOKP 197
#define NTOK  196
#define NC    768
#define NHID  192
#define NH    14
#define NVF   8        // rfft cols = 14/2+1
#define CHT   64       // channels per tile
#define NTILE 12       // 768/64
#define NCH   8        // C-chunks in k_mlp1
#define CCH   (NC / NCH)  // 96 channels per chunk

// twiddles (compile-time folded under full unroll)
constexpr float CT14[14] = {
    1.0f, 0.9009688679024191f, 0.6234898018587336f, 0.22252093395631445f,
    -0.22252093395631434f, -0.6234898018587335f, -0.9009688679024191f, -1.0f,
    -0.9009688679024191f, -0.6234898018587335f, -0.22252093395631434f,
    0.22252093395631445f, 0.6234898018587336f, 0.9009688679024191f};
constexpr float ST14[14] = {
    0.0f, 0.4338837391175581f, 0.7818314824680298f, 0.9749279121818236f,
    0.9749279121818236f, 0.7818314824680299f, 0.43388373911755823f, 0.0f,
    -0.43388373911755823f, -0.7818314824680299f, -0.9749279121818236f,
    -0.9749279121818236f, -0.7818314824680298f, -0.4338837391175581f};

// ---------------- K1: LayerNorm stats per (b, token) -> float2(mean, rstd) ----
__global__ __launch_bounds__(256) void k_stats(const float* __restrict__ x,
                                               float2* __restrict__ msv) {
  int row = blockIdx.x * 4 + (threadIdx.x >> 6);
  int lane = threadIdx.x & 63;
  if (row >= NB * NTOK) return;
  int b = row / NTOK, t = row - b * NTOK;
  const float4* p = (const float4*)(x + ((size_t)b * NTOKP + 1 + t) * NC);
  float s = 0.f, ss = 0.f;
#pragma unroll
  for (int k = 0; k < 3; ++k) {
    float4 v = p[lane + k * 64];
    s += v.x + v.y + v.z + v.w;
    ss += v.x * v.x + v.y * v.y + v.z * v.z + v.w * v.w;
  }
#pragma unroll
  for (int off = 32; off; off >>= 1) {
    s += __shfl_down(s, off);
    ss += __shfl_down(ss, off);
  }
  if (lane == 0) {
    float m = s * (1.f / NC);
    float var = ss * (1.f / NC) - m * m;
    msv[row] = make_float2(m, rsqrtf(var + 1e-5f));
  }
}

// ---------------- K2: forward DFT + energy (packed fp16, radix-2 stage B,
//                     software-pipelined x loads) ----------------
__global__ __launch_bounds__(256) void k_fwd(const float* __restrict__ x,
                                             const float* __restrict__ gamma,
                                             const float* __restrict__ beta,
                                             const float2* __restrict__ msv,
                                             float* __restrict__ energy) {
  __shared__ __half2 A[NH * NVF * CHT];  // [i][v][c] {re,im} fp16  28.7KB
  __shared__ float2 ms[NTOK];
  __shared__ float esum[256];
  int b = blockIdx.y, c0 = blockIdx.x * CHT, tid = threadIdx.x;
  int c = tid & 63, w = tid >> 6;

  for (int k = tid; k < NTOK; k += 256) ms[k] = msv[b * NTOK + k];
  float g = gamma[c0 + c], be = beta[c0 + c];

  // twiddle pair tables {cos,-sin}, {sin,cos}; omega7^t = omega14^(2t)
  __half2 TW1[14], TW2[14];
#pragma unroll
  for (int k = 0; k < 14; ++k) {
    TW1[k] = __floats2half2_rn(CT14[k], -ST14[k]);
    TW2[k] = __floats2half2_rn(ST14[k], CT14[k]);
  }
  __syncthreads();

  // stage A: per (c,i): A[i,v] = sum_j xn[i,j] e^{-2pi i v j/14}
  // loads for row i+4 are issued before computing row i (hide L3 latency)
  {
    const float* xb = x + ((size_t)b * NTOKP + 1) * NC + c0 + c;
    float xf[NH];
#pragma unroll
    for (int j = 0; j < NH; ++j) xf[j] = xb[(size_t)(w * NH + j) * NC];
#pragma unroll 1
    for (int i = w; i < NH; i += 4) {
      float xf2[NH];
      if (i + 4 < NH) {
#pragma unroll
        for (int j = 0; j < NH; ++j)
          xf2[j] = xb[(size_t)((i + 4) * NH + j) * NC];
      }
      __half2 xh[NH];
#pragma unroll
      for (int j = 0; j < NH; ++j) {
        float2 m = ms[i * NH + j];
        xh[j] = __float2half2_rn((xf[j] - m.x) * m.y * g + be);
      }
      __half2 acc[NVF];
#pragma unroll
      for (int v = 0; v < NVF; ++v) acc[v] = __floats2half2_rn(0.f, 0.f);
#pragma unroll
      for (int j = 0; j < NH; ++j) {
#pragma unroll
        for (int v = 0; v < NVF; ++v)
          acc[v] = __hfma2(xh[j], TW1[(v * j) % 14], acc[v]);
      }
#pragma unroll
      for (int v = 0; v < NVF; ++v) A[(i * NVF + v) * CHT + c] = acc[v];
#pragma unroll
      for (int j = 0; j < NH; ++j) xf[j] = xf2[j];
    }
  }
  __syncthreads();

  // stage B (radix-2 over i): S[u] = E[u%7] + w14^u * O[u%7]
  // energy via grouped logs: sum log1p(|S|/14) = log(prod(14+|S|)) - n*ln(14)
  float part = 0.f;
#pragma unroll 1
  for (int vv = 0; vv < 2; ++vv) {
    int v = w * 2 + vv;
    bool herm = (v == 0) || (v == 7);  // |S[14-u]| == |S[u]| in these columns
    const __half2* Ac = A + v * CHT + c;
    __half2 E[7], O[7];
#pragma unroll
    for (int k = 0; k < 7; ++k) {
      E[k] = __floats2half2_rn(0.f, 0.f);
      O[k] = __floats2half2_rn(0.f, 0.f);
    }
#pragma unroll
    for (int m = 0; m < 7; ++m) {
      __half2 ae = Ac[(2 * m) * NVF * CHT];
      __half2 ao = Ac[(2 * m + 1) * NVF * CHT];
      __half2 aer = __low2half2(ae), aei = __high2half2(ae);
      __half2 aor = __low2half2(ao), aoi = __high2half2(ao);
#pragma unroll
      for (int k = 0; k < 7; ++k) {
        int t = (2 * k * m) % 14;
        E[k] = __hfma2(aer, TW1[t], __hfma2(aei, TW2[t], E[k]));
        O[k] = __hfma2(aor, TW1[t], __hfma2(aoi, TW2[t], O[k]));
      }
    }
    float pa = 1.f, pb = 1.f;
#pragma unroll
    for (int u = 0; u < 14; ++u) {
      if (!herm || u < 8) {
        int k = u % 7;
        __half2 Ov = O[k];
        __half2 S = __hfma2(__low2half2(Ov), TW1[u],
                            __hfma2(__high2half2(Ov), TW2[u], E[k]));
        float2 s2 = __half22float2(S);
        float mag = 14.f + __builtin_amdgcn_sqrtf(fmaf(s2.x, s2.x, s2.y * s2.y));
        if (herm) {
          float msq = mag * mag;
          if (u == 0) {
            if (v == 7) pb *= mag;  // v==0,u==0 is DC: excluded
          } else if (u <= 3) {
            pa *= msq;              // u and 14-u counted together
          } else if (u <= 6) {
            pb *= msq;
          } else {
            pb *= mag;              // u==7 self-mirror
          }
        } else {
          if (u < 7) pa *= mag; else pb *= mag;
        }
      }
    }
    part += __logf(pa) + __logf(pb);
  }
  esum[tid] = part;
  __syncthreads();
  if (w == 0) {
    // 111 bins contributed per channel (112 minus DC); each carries -ln(14)
    float e = esum[c] + esum[c + 64] + esum[c + 128] + esum[c + 192];
    energy[(size_t)b * NC + c0 + c] =
        (e - 111.f * 2.6390573296152584f) * (1.f / 112.f);
  }
}

// ---------------- K3a: MLP layer-1 partials. 2048 blocks for TLP ----------------
__global__ __launch_bounds__(192) void k_mlp1(const float* __restrict__ energy,
                                              const float* __restrict__ w1,
                                              float* __restrict__ partial) {
  int s = blockIdx.x, b = blockIdx.y;
  int h = threadIdx.x;
  const float* ep = energy + (size_t)b * NC + s * CCH;
  const float* wp = w1 + (size_t)s * CCH * NHID + h;
  float acc = 0.f;
#pragma unroll 8
  for (int cc = 0; cc < CCH; ++cc)
    acc = fmaf(ep[cc], wp[(size_t)cc * NHID], acc);
  partial[((size_t)b * NCH + s) * NHID + h] = acc;
}

// ---------------- K3b: finalize MLP per batch ----------------
__global__ __launch_bounds__(192) void k_final(const float* __restrict__ partial,
                                               const float* __restrict__ b1,
                                               const float* __restrict__ w2,
                                               const float* __restrict__ b2,
                                               float* __restrict__ m2s) {
  __shared__ float2 sh[NHID];
  int b = blockIdx.x, h = threadIdx.x;
  float a = b1[h];
#pragma unroll
  for (int s = 0; s < NCH; ++s) a += partial[((size_t)b * NCH + s) * NHID + h];
  float ge = 0.5f * a * (1.f + erff(a * 0.70710678118654752f));  // exact gelu
  sh[h] = make_float2(ge * w2[2 * h], ge * w2[2 * h + 1]);
  __syncthreads();
  if (h < 64) {
    float p0 = sh[h].x + sh[h + 64].x + sh[h + 128].x;
    float p1 = sh[h].y + sh[h + 64].y + sh[h + 128].y;
#pragma unroll
    for (int off = 32; off; off >>= 1) {
      p0 += __shfl_down(p0, off);
      p1 += __shfl_down(p1, off);
    }
    if (h == 0) {
      float o0 = p0 + b2[0], o1 = p1 + b2[1];
      float muv = 9.899494936611665f / (1.f + expf(-o0));
      muv = fmaxf(muv, 1.f);
      float sp = (o1 > 20.f) ? o1 : log1pf(expf(o1));
      float sg = fmaxf(sp, 0.1f);
      m2s[b] = 2.f * muv * muv * sg + 1e-6f;
    }
  }
}

// ---------------- K4: separable circulant filter (packed fp16) + residual,
//                     software-pipelined x loads ----------------
// mask separable: exp(-(fy2[u]+fx2[v])/ms) = wexp[u]*wexp[v]
// filtered = K (x) K (x) xn  (mean path drops out: mask[0,0]=1 => K*const=const)
__global__ __launch_bounds__(256) void k_inv(const float* __restrict__ x,
                                             const float* __restrict__ gamma,
                                             const float* __restrict__ beta,
                                             const float2* __restrict__ msv,
                                             const float* __restrict__ m2s,
                                             const float* __restrict__ rscale,
                                             float* __restrict__ out) {
  __shared__ __half2 T[NH * 7 * CHT];  // y[i][{2jp,2jp+1}] fp16 pairs: 25KB
  __shared__ float2 ms[NTOK];
  __shared__ float wexp[NH];
  __shared__ float kc[NH];
  int b = blockIdx.y, c0 = blockIdx.x * CHT, tid = threadIdx.x;
  int c = tid & 63, w = tid >> 6;
  float rs = rscale[0];

  for (int k = tid; k < NTOK; k += 256) ms[k] = msv[b * NTOK + k];
  if (tid < CHT) {  // cls-token passthrough
    size_t idx = (size_t)b * NTOKP * NC + c0 + tid;
    out[idx] = x[idx];
  }
  float msb = m2s[b];
  if (tid < NH) {
    int f = (tid <= 7) ? tid : 14 - tid;
    wexp[tid] = __expf(-(float)(f * f) / msb);
  }
  __syncthreads();
  if (tid < NH) {
    float s = 0.f;
#pragma unroll
    for (int k = 0; k < NH; ++k) s = fmaf(wexp[k], CT14[(k * tid) % 14], s);
    kc[tid] = s * (1.f / 14.f);
  }
  float g = gamma[c0 + c], be = beta[c0 + c];
  __syncthreads();

  float kr[NH];
#pragma unroll
  for (int d = 0; d < NH; ++d) kr[d] = kc[d];
  // packed kernel-pair table: khp[d] = {kr[d], kr[(d+1)%14]}
  __half2 khp[NH];
#pragma unroll
  for (int d = 0; d < NH; ++d) khp[d] = __floats2half2_rn(kr[d], kr[(d + 1) % 14]);

  const float* xb = x + ((size_t)b * NTOKP + 1) * NC + c0 + c;

  // stage 1: per (c,i): {y0,y1}[jp] = sum_j xn[i,j] * {kr[(2jp-j)%14], kr[(2jp+1-j)%14]}
  // loads for row i+4 issued before computing row i
  {
    float xf[NH];
#pragma unroll
    for (int j = 0; j < NH; ++j) xf[j] = xb[(size_t)(w * NH + j) * NC];
#pragma unroll 1
    for (int i = w; i < NH; i += 4) {
      float xf2[NH];
      if (i + 4 < NH) {
#pragma unroll
        for (int j = 0; j < NH; ++j)
          xf2[j] = xb[(size_t)((i + 4) * NH + j) * NC];
      }
      __half2 xh[NH];
#pragma unroll
      for (int j = 0; j < NH; ++j) {
        float2 m = ms[i * NH + j];
        xh[j] = __float2half2_rn((xf[j] - m.x) * m.y * g + be);
      }
#pragma unroll
      for (int jp = 0; jp < 7; ++jp) {
        __half2 acc = __floats2half2_rn(0.f, 0.f);
#pragma unroll
        for (int j = 0; j < NH; ++j)
          acc = __hfma2(xh[j], khp[(2 * jp - j + 28) % 14], acc);
        T[(i * 7 + jp) * CHT + c] = acc;
      }
#pragma unroll
      for (int j = 0; j < NH; ++j) xf[j] = xf2[j];
    }
  }
  __syncthreads();

  // stage 2: per (c,jq): {z[2d],z[2d+1]} = sum_i y[i,jq] * khp[(2d-i)%14]
  // x row for jq+4 prefetched while computing jq
  {
    float xf[NH];
#pragma unroll
    for (int ii = 0; ii < NH; ++ii) xf[ii] = xb[(size_t)(ii * NH + w) * NC];
#pragma unroll 1
    for (int jq = w; jq < NH; jq += 4) {
      float xf2[NH];
      if (jq + 4 < NH) {
#pragma unroll
        for (int ii = 0; ii < NH; ++ii)
          xf2[ii] = xb[(size_t)(ii * NH + jq + 4) * NC];
      }
      int jp = jq >> 1, hi = jq & 1;
      __half2 acc2[7];
#pragma unroll
      for (int d = 0; d < 7; ++d) acc2[d] = __floats2half2_rn(0.f, 0.f);
#pragma unroll
      for (int i = 0; i < NH; ++i) {
        __half2 t = T[(i * 7 + jp) * CHT + c];
        __half2 yi = hi ? __high2half2(t) : __low2half2(t);  // wave-uniform select
#pragma unroll
        for (int d = 0; d < 7; ++d)
          acc2[d] = __hfma2(yi, khp[(2 * d - i + 28) % 14], acc2[d]);
      }
      float* outr = out + ((size_t)b * NTOKP + 1 + jq) * NC + c0 + c;
#pragma unroll
      for (int ii = 0; ii < NH; ++ii) {
        float z = (ii & 1) ? __high2float(acc2[ii >> 1]) : __low2float(acc2[ii >> 1]);
        float xv = xf[ii];
        float2 m = ms[ii * NH + jq];
        float xn = (xv - m.x) * m.y * g + be;
        outr[(size_t)ii * NH * NC] = xv + rs * (z - xn);
      }
#pragma unroll
      for (int ii = 0; ii < NH; ++ii) xf[ii] = xf2[ii];
    }
  }
}

extern "C" void kernel_launch(void* const* d_in, const int* in_sizes, int n_in,
                              void* d_out, int out_size, void* d_ws, size_t ws_size,
                              hipStream_t stream) {
  (void)in_sizes; (void)n_in; (void)out_size; (void)ws_size;
  const float* x      = (const float*)d_in[0];
  const float* gamma  = (const float*)d_in[1];
  const float* beta   = (const float*)d_in[2];
  const float* w1     = (const float*)d_in[3];
  const float* b1     = (const float*)d_in[4];
  const float* w2     = (const float*)d_in[5];
  const float* b2     = (const float*)d_in[6];
  const float* rscale = (const float*)d_in[7];
  float* out = (float*)d_out;

  char* wsb = (char*)d_ws;
  float2* msv    = (float2*)(wsb + 0);        //   401,408 B
  float* energy  = (float*)(wsb + 401408);    //   786,432 B  [NB][NC]
  float* partial = (float*)(wsb + 1187840);   // 1,572,864 B  [NB][NCH][NHID]
  float* m2s     = (float*)(wsb + 2760704);   //     1,024 B

  k_stats<<<(NB * NTOK + 3) / 4, 256, 0, stream>>>(x, msv);
  k_fwd<<<dim3(NTILE, NB), 256, 0, stream>>>(x, gamma, beta, msv, energy);
  k_mlp1<<<dim3(NCH, NB), 192, 0, stream>>>(energy, w1, partial);
  k_final<<<NB, 192, 0, stream>>>(partial, b1, w2, b2, m2s);
  k_inv<<<dim3(NTILE, NB), 256, 0, stream>>>(x, gamma, beta, msv, m2s, rscale,
                                             out);
}

// Round 13
// 140.571 us; speedup vs baseline: 1.0434x; 1.0434x over previous
//
#include <hip/hip_runtime.h>
#include <hip/hip_fp16.h>
#include <math.h>

// ---------------- problem constants ----------------
#define NB    256
#define NTOKP 197
#define NTOK  196
#define NC    768
#define NHID  192
#define NH    14
#define NVF   8        // rfft cols = 14/2+1
#define CHT   64       // channels per tile
#define NTILE 12       // 768/64
#define NCH   8        // C-chunks in k_mlp1
#define CCH   (NC / NCH)  // 96 channels per chunk

// twiddles (compile-time folded under full unroll)
constexpr float CT14[14] = {
    1.0f, 0.9009688679024191f, 0.6234898018587336f, 0.22252093395631445f,
    -0.22252093395631434f, -0.6234898018587335f, -0.9009688679024191f, -1.0f,
    -0.9009688679024191f, -0.6234898018587335f, -0.22252093395631434f,
    0.22252093395631445f, 0.6234898018587336f, 0.9009688679024191f};
constexpr float ST14[14] = {
    0.0f, 0.4338837391175581f, 0.7818314824680298f, 0.9749279121818236f,
    0.9749279121818236f, 0.7818314824680299f, 0.43388373911755823f, 0.0f,
    -0.43388373911755823f, -0.7818314824680299f, -0.9749279121818236f,
    -0.9749279121818236f, -0.7818314824680298f, -0.4338837391175581f};

__device__ __forceinline__ unsigned int h2bits(__half2 h) {
  return *(unsigned int*)&h;
}

// ---------------- K1: LN stats (+ optional fp16 xn write) ----------------
template <bool WH>
__global__ __launch_bounds__(256) void k_stats(const float* __restrict__ x,
                                               const float* __restrict__ gamma,
                                               const float* __restrict__ beta,
                                               float2* __restrict__ msv,
                                               __half* __restrict__ xnh) {
  int row = blockIdx.x * 4 + (threadIdx.x >> 6);
  int lane = threadIdx.x & 63;
  if (row >= NB * NTOK) return;
  int b = row / NTOK, t = row - b * NTOK;
  const float4* p = (const float4*)(x + ((size_t)b * NTOKP + 1 + t) * NC);
  float4 v[3];
  float s = 0.f, ss = 0.f;
#pragma unroll
  for (int k = 0; k < 3; ++k) {
    v[k] = p[lane + k * 64];
    s += v[k].x + v[k].y + v[k].z + v[k].w;
    ss += v[k].x * v[k].x + v[k].y * v[k].y + v[k].z * v[k].z + v[k].w * v[k].w;
  }
#pragma unroll
  for (int m = 32; m; m >>= 1) {
    s += __shfl_xor(s, m);
    ss += __shfl_xor(ss, m);
  }
  float mean = s * (1.f / NC);
  float var = ss * (1.f / NC) - mean * mean;
  float rstd = rsqrtf(var + 1e-5f);
  if (lane == 0) msv[row] = make_float2(mean, rstd);
  if (WH) {
#pragma unroll
    for (int k = 0; k < 3; ++k) {
      float4 g = ((const float4*)gamma)[lane + k * 64];
      float4 be = ((const float4*)beta)[lane + k * 64];
      float4 xn;
      xn.x = (v[k].x - mean) * rstd * g.x + be.x;
      xn.y = (v[k].y - mean) * rstd * g.y + be.y;
      xn.z = (v[k].z - mean) * rstd * g.z + be.z;
      xn.w = (v[k].w - mean) * rstd * g.w + be.w;
      uint2 u = make_uint2(h2bits(__floats2half2_rn(xn.x, xn.y)),
                           h2bits(__floats2half2_rn(xn.z, xn.w)));
      *(uint2*)(xnh + (size_t)row * NC + lane * 4 + k * 256) = u;
    }
  }
}

// ---------------- K2: forward DFT + energy (packed fp16, radix-2 stage B) ----
template <bool UH>
__global__ __launch_bounds__(256) void k_fwd(const float* __restrict__ x,
                                             const __half* __restrict__ xnh,
                                             const float* __restrict__ gamma,
                                             const float* __restrict__ beta,
                                             const float2* __restrict__ msv,
                                             float* __restrict__ energy) {
  __shared__ __half2 A[NH * NVF * CHT];  // [i][v][c] {re,im} fp16  28.7KB
  __shared__ float2 ms[UH ? 1 : NTOK];
  __shared__ float esum[256];
  int b = blockIdx.y, c0 = blockIdx.x * CHT, tid = threadIdx.x;
  int c = tid & 63, w = tid >> 6;

  float g = 0.f, be = 0.f;
  if (!UH) {
    for (int k = tid; k < NTOK; k += 256) ms[k] = msv[b * NTOK + k];
    g = gamma[c0 + c];
    be = beta[c0 + c];
  }

  // twiddle pair tables {cos,-sin}, {sin,cos}; omega7^t = omega14^(2t)
  __half2 TW1[14], TW2[14];
#pragma unroll
  for (int k = 0; k < 14; ++k) {
    TW1[k] = __floats2half2_rn(CT14[k], -ST14[k]);
    TW2[k] = __floats2half2_rn(ST14[k], CT14[k]);
  }
  __syncthreads();

  // stage A: per (c,i): A[i,v] = sum_j xn[i,j] e^{-2pi i v j/14}
#pragma unroll 1
  for (int i = w; i < NH; i += 4) {
    __half2 xh[NH];
    if (UH) {
      const __half* xr = xnh + ((size_t)b * NTOK + i * NH) * NC + c0 + c;
#pragma unroll
      for (int j = 0; j < NH; ++j) xh[j] = __half2half2(xr[(size_t)j * NC]);
    } else {
      const float* xr = x + ((size_t)b * NTOKP + 1 + i * NH) * NC + c0 + c;
#pragma unroll
      for (int j = 0; j < NH; ++j) {
        float2 m = ms[i * NH + j];
        xh[j] = __float2half2_rn((xr[(size_t)j * NC] - m.x) * m.y * g + be);
      }
    }
    __half2 acc[NVF];
#pragma unroll
    for (int v = 0; v < NVF; ++v) acc[v] = __floats2half2_rn(0.f, 0.f);
#pragma unroll
    for (int j = 0; j < NH; ++j) {
#pragma unroll
      for (int v = 0; v < NVF; ++v)
        acc[v] = __hfma2(xh[j], TW1[(v * j) % 14], acc[v]);
    }
#pragma unroll
    for (int v = 0; v < NVF; ++v) A[(i * NVF + v) * CHT + c] = acc[v];
  }
  __syncthreads();

  // stage B (radix-2 over i): S[u] = E[u%7] + w14^u * O[u%7]
  // energy via grouped logs: sum log1p(|S|/14) = log(prod(14+|S|)) - n*ln(14)
  float part = 0.f;
#pragma unroll 1
  for (int vv = 0; vv < 2; ++vv) {
    int v = w * 2 + vv;
    bool herm = (v == 0) || (v == 7);  // |S[14-u]| == |S[u]| in these columns
    const __half2* Ac = A + v * CHT + c;
    __half2 E[7], O[7];
#pragma unroll
    for (int k = 0; k < 7; ++k) {
      E[k] = __floats2half2_rn(0.f, 0.f);
      O[k] = __floats2half2_rn(0.f, 0.f);
    }
#pragma unroll
    for (int m = 0; m < 7; ++m) {
      __half2 ae = Ac[(2 * m) * NVF * CHT];
      __half2 ao = Ac[(2 * m + 1) * NVF * CHT];
      __half2 aer = __low2half2(ae), aei = __high2half2(ae);
      __half2 aor = __low2half2(ao), aoi = __high2half2(ao);
#pragma unroll
      for (int k = 0; k < 7; ++k) {
        int t = (2 * k * m) % 14;
        E[k] = __hfma2(aer, TW1[t], __hfma2(aei, TW2[t], E[k]));
        O[k] = __hfma2(aor, TW1[t], __hfma2(aoi, TW2[t], O[k]));
      }
    }
    float pa = 1.f, pb = 1.f;
#pragma unroll
    for (int u = 0; u < 14; ++u) {
      if (!herm || u < 8) {
        int k = u % 7;
        __half2 Ov = O[k];
        __half2 S = __hfma2(__low2half2(Ov), TW1[u],
                            __hfma2(__high2half2(Ov), TW2[u], E[k]));
        float2 s2 = __half22float2(S);
        float mag = 14.f + __builtin_amdgcn_sqrtf(fmaf(s2.x, s2.x, s2.y * s2.y));
        if (herm) {
          float msq = mag * mag;
          if (u == 0) {
            if (v == 7) pb *= mag;  // v==0,u==0 is DC: excluded
          } else if (u <= 3) {
            pa *= msq;              // u and 14-u counted together
          } else if (u <= 6) {
            pb *= msq;
          } else {
            pb *= mag;              // u==7 self-mirror
          }
        } else {
          if (u < 7) pa *= mag; else pb *= mag;
        }
      }
    }
    part += __logf(pa) + __logf(pb);
  }
  esum[tid] = part;
  __syncthreads();
  if (w == 0) {
    // 111 bins contributed per channel (112 minus DC); each carries -ln(14)
    float e = esum[c] + esum[c + 64] + esum[c + 128] + esum[c + 192];
    energy[(size_t)b * NC + c0 + c] =
        (e - 111.f * 2.6390573296152584f) * (1.f / 112.f);
  }
}

// ---------------- K3a: MLP layer-1 partials. 2048 blocks for TLP ----------------
__global__ __launch_bounds__(192) void k_mlp1(const float* __restrict__ energy,
                                              const float* __restrict__ w1,
                                              float* __restrict__ partial) {
  int s = blockIdx.x, b = blockIdx.y;
  int h = threadIdx.x;
  const float* ep = energy + (size_t)b * NC + s * CCH;
  const float* wp = w1 + (size_t)s * CCH * NHID + h;
  float acc = 0.f;
#pragma unroll 8
  for (int cc = 0; cc < CCH; ++cc)
    acc = fmaf(ep[cc], wp[(size_t)cc * NHID], acc);
  partial[((size_t)b * NCH + s) * NHID + h] = acc;
}

// ---------------- K3b: finalize MLP per batch ----------------
__global__ __launch_bounds__(192) void k_final(const float* __restrict__ partial,
                                               const float* __restrict__ b1,
                                               const float* __restrict__ w2,
                                               const float* __restrict__ b2,
                                               float* __restrict__ m2s) {
  __shared__ float2 sh[NHID];
  int b = blockIdx.x, h = threadIdx.x;
  float a = b1[h];
#pragma unroll
  for (int s = 0; s < NCH; ++s) a += partial[((size_t)b * NCH + s) * NHID + h];
  float ge = 0.5f * a * (1.f + erff(a * 0.70710678118654752f));  // exact gelu
  sh[h] = make_float2(ge * w2[2 * h], ge * w2[2 * h + 1]);
  __syncthreads();
  if (h < 64) {
    float p0 = sh[h].x + sh[h + 64].x + sh[h + 128].x;
    float p1 = sh[h].y + sh[h + 64].y + sh[h + 128].y;
#pragma unroll
    for (int off = 32; off; off >>= 1) {
      p0 += __shfl_down(p0, off);
      p1 += __shfl_down(p1, off);
    }
    if (h == 0) {
      float o0 = p0 + b2[0], o1 = p1 + b2[1];
      float muv = 9.899494936611665f / (1.f + expf(-o0));
      muv = fmaxf(muv, 1.f);
      float sp = (o1 > 20.f) ? o1 : log1pf(expf(o1));
      float sg = fmaxf(sp, 0.1f);
      m2s[b] = 2.f * muv * muv * sg + 1e-6f;
    }
  }
}

// ---------------- K4: separable circulant filter (packed fp16) + residual ----
// mask separable: exp(-(fy2[u]+fx2[v])/ms) = wexp[u]*wexp[v]
// filtered = K (x) K (x) xn  (mean path drops out: mask[0,0]=1 => K*const=const)
// UH: xv reconstructed from fp16 xn: xv = (xn-beta)/gamma * (1/rstd) + mean
template <bool UH>
__global__ __launch_bounds__(256) void k_inv(const float* __restrict__ x,
                                             const __half* __restrict__ xnh,
                                             const float* __restrict__ gamma,
                                             const float* __restrict__ beta,
                                             const float2* __restrict__ msv,
                                             const float* __restrict__ m2s,
                                             const float* __restrict__ rscale,
                                             float* __restrict__ out) {
  __shared__ __half2 T[NH * 7 * CHT];  // y[i][{2jp,2jp+1}] fp16 pairs: 25KB
  __shared__ float2 ms[NTOK];          // (mean, rstd)
  __shared__ float rr[UH ? NTOK : 1];  // 1/rstd (UH reconstruction)
  __shared__ float wexp[NH];
  __shared__ float kc[NH];
  int b = blockIdx.y, c0 = blockIdx.x * CHT, tid = threadIdx.x;
  int c = tid & 63, w = tid >> 6;
  float rs = rscale[0];

  for (int k = tid; k < NTOK; k += 256) {
    float2 m = msv[b * NTOK + k];
    ms[k] = m;
    if (UH) rr[k] = 1.f / m.y;
  }
  if (tid < CHT) {  // cls-token passthrough
    size_t idx = (size_t)b * NTOKP * NC + c0 + tid;
    out[idx] = x[idx];
  }
  float msb = m2s[b];
  if (tid < NH) {
    int f = (tid <= 7) ? tid : 14 - tid;
    wexp[tid] = __expf(-(float)(f * f) / msb);
  }
  __syncthreads();
  if (tid < NH) {
    float s = 0.f;
#pragma unroll
    for (int k = 0; k < NH; ++k) s = fmaf(wexp[k], CT14[(k * tid) % 14], s);
    kc[tid] = s * (1.f / 14.f);
  }
  float g = gamma[c0 + c], be = beta[c0 + c];
  float rg = 1.f / g;
  __syncthreads();

  float kr[NH];
#pragma unroll
  for (int d = 0; d < NH; ++d) kr[d] = kc[d];
  // packed kernel-pair table: khp[d] = {kr[d], kr[(d+1)%14]}
  __half2 khp[NH];
#pragma unroll
  for (int d = 0; d < NH; ++d) khp[d] = __floats2half2_rn(kr[d], kr[(d + 1) % 14]);

  // stage 1: per (c,i): {y0,y1}[jp] = sum_j xn[i,j] * {kr[(2jp-j)%14], kr[(2jp+1-j)%14]}
#pragma unroll 1
  for (int i = w; i < NH; i += 4) {
    __half2 xh[NH];
    if (UH) {
      const __half* xr = xnh + ((size_t)b * NTOK + i * NH) * NC + c0 + c;
#pragma unroll
      for (int j = 0; j < NH; ++j) xh[j] = __half2half2(xr[(size_t)j * NC]);
    } else {
      const float* xr = x + ((size_t)b * NTOKP + 1 + i * NH) * NC + c0 + c;
#pragma unroll
      for (int j = 0; j < NH; ++j) {
        float2 m = ms[i * NH + j];
        xh[j] = __float2half2_rn((xr[(size_t)j * NC] - m.x) * m.y * g + be);
      }
    }
#pragma unroll
    for (int jp = 0; jp < 7; ++jp) {
      __half2 acc = __floats2half2_rn(0.f, 0.f);
#pragma unroll
      for (int j = 0; j < NH; ++j)
        acc = __hfma2(xh[j], khp[(2 * jp - j + 28) % 14], acc);
      T[(i * 7 + jp) * CHT + c] = acc;
    }
  }
  __syncthreads();

  // stage 2: per (c,jq): {z[2d],z[2d+1]} = sum_i y[i,jq] * khp[(2d-i)%14]
#pragma unroll 1
  for (int jq = w; jq < NH; jq += 4) {
    int jp = jq >> 1, hi = jq & 1;
    __half2 acc2[7];
#pragma unroll
    for (int d = 0; d < 7; ++d) acc2[d] = __floats2half2_rn(0.f, 0.f);
#pragma unroll
    for (int i = 0; i < NH; ++i) {
      __half2 t = T[(i * 7 + jp) * CHT + c];
      __half2 yi = hi ? __high2half2(t) : __low2half2(t);  // wave-uniform select
#pragma unroll
      for (int d = 0; d < 7; ++d)
        acc2[d] = __hfma2(yi, khp[(2 * d - i + 28) % 14], acc2[d]);
    }
    float* outr = out + ((size_t)b * NTOKP + 1 + jq) * NC + c0 + c;
    const __half* xq = xnh + ((size_t)b * NTOK + jq) * NC + c0 + c;
    const float* xr = x + ((size_t)b * NTOKP + 1 + jq) * NC + c0 + c;
#pragma unroll
    for (int ii = 0; ii < NH; ++ii) {
      float z = (ii & 1) ? __high2float(acc2[ii >> 1]) : __low2float(acc2[ii >> 1]);
      if (UH) {
        float xnv = __half2float(xq[(size_t)ii * NH * NC]);
        int t = ii * NH + jq;
        float xv = fmaf((xnv - be) * rg, rr[t], ms[t].x);
        outr[(size_t)ii * NH * NC] = xv + rs * (z - xnv);
      } else {
        float xv = xr[(size_t)ii * NH * NC];
        float2 m = ms[ii * NH + jq];
        float xn = (xv - m.x) * m.y * g + be;
        outr[(size_t)ii * NH * NC] = xv + rs * (z - xn);
      }
    }
  }
}

extern "C" void kernel_launch(void* const* d_in, const int* in_sizes, int n_in,
                              void* d_out, int out_size, void* d_ws, size_t ws_size,
                              hipStream_t stream) {
  (void)in_sizes; (void)n_in; (void)out_size;
  const float* x      = (const float*)d_in[0];
  const float* gamma  = (const float*)d_in[1];
  const float* beta   = (const float*)d_in[2];
  const float* w1     = (const float*)d_in[3];
  const float* b1     = (const float*)d_in[4];
  const float* w2     = (const float*)d_in[5];
  const float* b2     = (const float*)d_in[6];
  const float* rscale = (const float*)d_in[7];
  float* out = (float*)d_out;

  char* wsb = (char*)d_ws;
  float2* msv = (float2*)(wsb + 0);        //   401,408 B
  float* m2s  = (float*)(wsb + 401408);    //     1,024 B
  __half* xnh = (__half*)(wsb + 402432);   // 77,070,336 B
  size_t need = 402432 + (size_t)NB * NTOK * NC * 2;  // 77.5 MB
  bool useH = ws_size >= need;

  // energy & partial live in d_out's tail; k_inv fully overwrites out afterwards.
  // out bytes = 256*197*768*4 = 154,828,800
  float* energy  = (float*)((char*)d_out + 150994944);  //   786,432 B -> 151,781,376
  float* partial = (float*)((char*)d_out + 152043520);  // 1,572,864 B -> 153,616,384

  if (useH) {
    k_stats<true><<<NB * NTOK / 4, 256, 0, stream>>>(x, gamma, beta, msv, xnh);
    k_fwd<true><<<dim3(NTILE, NB), 256, 0, stream>>>(x, xnh, gamma, beta, msv,
                                                     energy);
  } else {
    k_stats<false><<<NB * NTOK / 4, 256, 0, stream>>>(x, gamma, beta, msv, xnh);
    k_fwd<false><<<dim3(NTILE, NB), 256, 0, stream>>>(x, xnh, gamma, beta, msv,
                                                      energy);
  }
  k_mlp1<<<dim3(NCH, NB), 192, 0, stream>>>(energy, w1, partial);
  k_final<<<NB, 192, 0, stream>>>(partial, b1, w2, b2, m2s);
  if (useH) {
    k_inv<true><<<dim3(NTILE, NB), 256, 0, stream>>>(x, xnh, gamma, beta, msv,
                                                     m2s, rscale, out);
  } else {
    k_inv<false><<<dim3(NTILE, NB), 256, 0, stream>>>(x, xnh, gamma, beta, msv,
                                                      m2s, rscale, out);
  }
}

// Round 14
// 137.059 us; speedup vs baseline: 1.0702x; 1.0256x over previous
//
#include <hip/hip_runtime.h>
#include <hip/hip_fp16.h>
#include <math.h>

// ---------------- problem constants ----------------
#define NB    256
#define NTOKP 197
#define NTOK  196
#define NC    768
#define NHID  192
#define NH    14
#define NVF   8        // rfft cols = 14/2+1
#define CHT   64       // channels per tile
#define NTILE 12       // 768/64

// twiddles (compile-time folded under full unroll)
constexpr float CT14[14] = {
    1.0f, 0.9009688679024191f, 0.6234898018587336f, 0.22252093395631445f,
    -0.22252093395631434f, -0.6234898018587335f, -0.9009688679024191f, -1.0f,
    -0.9009688679024191f, -0.6234898018587335f, -0.22252093395631434f,
    0.22252093395631445f, 0.6234898018587336f, 0.9009688679024191f};
constexpr float ST14[14] = {
    0.0f, 0.4338837391175581f, 0.7818314824680298f, 0.9749279121818236f,
    0.9749279121818236f, 0.7818314824680299f, 0.43388373911755823f, 0.0f,
    -0.43388373911755823f, -0.7818314824680299f, -0.9749279121818236f,
    -0.9749279121818236f, -0.7818314824680298f, -0.4338837391175581f};

__device__ __forceinline__ unsigned int h2bits(__half2 h) {
  return *(unsigned int*)&h;
}

// ---------------- K1: LN stats (+ optional fp16 xn write) ----------------
template <bool WH>
__global__ __launch_bounds__(256) void k_stats(const float* __restrict__ x,
                                               const float* __restrict__ gamma,
                                               const float* __restrict__ beta,
                                               float2* __restrict__ msv,
                                               __half* __restrict__ xnh) {
  int row = blockIdx.x * 4 + (threadIdx.x >> 6);
  int lane = threadIdx.x & 63;
  if (row >= NB * NTOK) return;
  int b = row / NTOK, t = row - b * NTOK;
  const float4* p = (const float4*)(x + ((size_t)b * NTOKP + 1 + t) * NC);
  float4 v[3];
  float s = 0.f, ss = 0.f;
#pragma unroll
  for (int k = 0; k < 3; ++k) {
    v[k] = p[lane + k * 64];
    s += v[k].x + v[k].y + v[k].z + v[k].w;
    ss += v[k].x * v[k].x + v[k].y * v[k].y + v[k].z * v[k].z + v[k].w * v[k].w;
  }
#pragma unroll
  for (int m = 32; m; m >>= 1) {
    s += __shfl_xor(s, m);
    ss += __shfl_xor(ss, m);
  }
  float mean = s * (1.f / NC);
  float var = ss * (1.f / NC) - mean * mean;
  float rstd = rsqrtf(var + 1e-5f);
  if (lane == 0) msv[row] = make_float2(mean, rstd);
  if (WH) {
#pragma unroll
    for (int k = 0; k < 3; ++k) {
      float4 g = ((const float4*)gamma)[lane + k * 64];
      float4 be = ((const float4*)beta)[lane + k * 64];
      float4 xn;
      xn.x = (v[k].x - mean) * rstd * g.x + be.x;
      xn.y = (v[k].y - mean) * rstd * g.y + be.y;
      xn.z = (v[k].z - mean) * rstd * g.z + be.z;
      xn.w = (v[k].w - mean) * rstd * g.w + be.w;
      uint2 u = make_uint2(h2bits(__floats2half2_rn(xn.x, xn.y)),
                           h2bits(__floats2half2_rn(xn.z, xn.w)));
      *(uint2*)(xnh + (size_t)row * NC + lane * 4 + k * 256) = u;
    }
  }
}

// ---------------- K2: forward DFT + energy + fused MLP layer-1 partial ------
template <bool UH>
__global__ __launch_bounds__(256) void k_fwd(const float* __restrict__ x,
                                             const __half* __restrict__ xnh,
                                             const float* __restrict__ gamma,
                                             const float* __restrict__ beta,
                                             const float2* __restrict__ msv,
                                             const float* __restrict__ w1,
                                             __half* __restrict__ partial) {
  __shared__ __half2 A[NH * NVF * CHT];  // [i][v][c] {re,im} fp16  28.7KB
  __shared__ float2 ms[UH ? 1 : NTOK];
  __shared__ float esum[256];
  __shared__ float el[CHT];
  int b = blockIdx.y, c0 = blockIdx.x * CHT, tid = threadIdx.x;
  int c = tid & 63, w = tid >> 6;

  float g = 0.f, be = 0.f;
  if (!UH) {
    for (int k = tid; k < NTOK; k += 256) ms[k] = msv[b * NTOK + k];
    g = gamma[c0 + c];
    be = beta[c0 + c];
  }

  // twiddle pair tables {cos,-sin}, {sin,cos}; omega7^t = omega14^(2t)
  __half2 TW1[14], TW2[14];
#pragma unroll
  for (int k = 0; k < 14; ++k) {
    TW1[k] = __floats2half2_rn(CT14[k], -ST14[k]);
    TW2[k] = __floats2half2_rn(ST14[k], CT14[k]);
  }
  __syncthreads();

  // stage A: per (c,i): A[i,v] = sum_j xn[i,j] e^{-2pi i v j/14}
#pragma unroll 1
  for (int i = w; i < NH; i += 4) {
    __half2 xh[NH];
    if (UH) {
      const __half* xr = xnh + ((size_t)b * NTOK + i * NH) * NC + c0 + c;
#pragma unroll
      for (int j = 0; j < NH; ++j) xh[j] = __half2half2(xr[(size_t)j * NC]);
    } else {
      const float* xr = x + ((size_t)b * NTOKP + 1 + i * NH) * NC + c0 + c;
#pragma unroll
      for (int j = 0; j < NH; ++j) {
        float2 m = ms[i * NH + j];
        xh[j] = __float2half2_rn((xr[(size_t)j * NC] - m.x) * m.y * g + be);
      }
    }
    __half2 acc[NVF];
#pragma unroll
    for (int v = 0; v < NVF; ++v) acc[v] = __floats2half2_rn(0.f, 0.f);
#pragma unroll
    for (int j = 0; j < NH; ++j) {
#pragma unroll
      for (int v = 0; v < NVF; ++v)
        acc[v] = __hfma2(xh[j], TW1[(v * j) % 14], acc[v]);
    }
#pragma unroll
    for (int v = 0; v < NVF; ++v) A[(i * NVF + v) * CHT + c] = acc[v];
  }
  __syncthreads();

  // stage B (radix-2 over i): S[u] = E[u%7] + w14^u * O[u%7]
  // energy via grouped logs: sum log1p(|S|/14) = log(prod(14+|S|)) - n*ln(14)
  float part = 0.f;
#pragma unroll 1
  for (int vv = 0; vv < 2; ++vv) {
    int v = w * 2 + vv;
    bool herm = (v == 0) || (v == 7);  // |S[14-u]| == |S[u]| in these columns
    const __half2* Ac = A + v * CHT + c;
    __half2 E[7], O[7];
#pragma unroll
    for (int k = 0; k < 7; ++k) {
      E[k] = __floats2half2_rn(0.f, 0.f);
      O[k] = __floats2half2_rn(0.f, 0.f);
    }
#pragma unroll
    for (int m = 0; m < 7; ++m) {
      __half2 ae = Ac[(2 * m) * NVF * CHT];
      __half2 ao = Ac[(2 * m + 1) * NVF * CHT];
      __half2 aer = __low2half2(ae), aei = __high2half2(ae);
      __half2 aor = __low2half2(ao), aoi = __high2half2(ao);
#pragma unroll
      for (int k = 0; k < 7; ++k) {
        int t = (2 * k * m) % 14;
        E[k] = __hfma2(aer, TW1[t], __hfma2(aei, TW2[t], E[k]));
        O[k] = __hfma2(aor, TW1[t], __hfma2(aoi, TW2[t], O[k]));
      }
    }
    float pa = 1.f, pb = 1.f;
#pragma unroll
    for (int u = 0; u < 14; ++u) {
      if (!herm || u < 8) {
        int k = u % 7;
        __half2 Ov = O[k];
        __half2 S = __hfma2(__low2half2(Ov), TW1[u],
                            __hfma2(__high2half2(Ov), TW2[u], E[k]));
        float2 s2 = __half22float2(S);
        float mag = 14.f + __builtin_amdgcn_sqrtf(fmaf(s2.x, s2.x, s2.y * s2.y));
        if (herm) {
          float msq = mag * mag;
          if (u == 0) {
            if (v == 7) pb *= mag;  // v==0,u==0 is DC: excluded
          } else if (u <= 3) {
            pa *= msq;              // u and 14-u counted together
          } else if (u <= 6) {
            pb *= msq;
          } else {
            pb *= mag;              // u==7 self-mirror
          }
        } else {
          if (u < 7) pa *= mag; else pb *= mag;
        }
      }
    }
    part += __logf(pa) + __logf(pb);
  }
  esum[tid] = part;
  __syncthreads();
  if (w == 0) {
    // 111 bins contributed per channel (112 minus DC); each carries -ln(14)
    float e = esum[c] + esum[c + 64] + esum[c + 128] + esum[c + 192];
    el[c] = (e - 111.f * 2.6390573296152584f) * (1.f / 112.f);
  }
  __syncthreads();
  // fused MLP layer-1 partial for this 64-channel tile (w1 rows L2-resident)
  if (tid < NHID) {
    float acc = 0.f;
#pragma unroll 8
    for (int cc = 0; cc < CHT; ++cc)
      acc = fmaf(el[cc], w1[(size_t)(c0 + cc) * NHID + tid], acc);
    partial[((size_t)b * NTILE + blockIdx.x) * NHID + tid] = __float2half(acc);
  }
}

// ---------------- K3: separable circulant filter + residual,
//                     fused MLP finalize (per-block, redundant x12) ----------
// mask separable: exp(-(fy2[u]+fx2[v])/ms) = wexp[u]*wexp[v]
// filtered = K (x) K (x) xn  (mean path drops out: mask[0,0]=1 => K*const=const)
// UH: xv reconstructed from fp16 xn: xv = (xn-beta)/gamma * (1/rstd) + mean
template <bool UH>
__global__ __launch_bounds__(256) void k_inv(const float* __restrict__ x,
                                             const __half* __restrict__ xnh,
                                             const float* __restrict__ gamma,
                                             const float* __restrict__ beta,
                                             const float2* __restrict__ msv,
                                             const __half* __restrict__ partial,
                                             const float* __restrict__ b1,
                                             const float* __restrict__ w2,
                                             const float* __restrict__ b2,
                                             const float* __restrict__ rscale,
                                             float* __restrict__ out) {
  __shared__ __half2 T[NH * 7 * CHT];  // y[i][{2jp,2jp+1}] fp16 pairs: 25KB
  __shared__ float2 ms[NTOK];          // (mean, rstd)
  __shared__ float rr[UH ? NTOK : 1];  // 1/rstd (UH reconstruction)
  __shared__ float wexp[NH];
  __shared__ float kc[NH];
  __shared__ float2 sh2[NHID];
  __shared__ float msb_sh;
  int b = blockIdx.y, c0 = blockIdx.x * CHT, tid = threadIdx.x;
  int c = tid & 63, w = tid >> 6;
  float rs = rscale[0];

  for (int k = tid; k < NTOK; k += 256) {
    float2 m = msv[b * NTOK + k];
    ms[k] = m;
    if (UH) rr[k] = 1.f / m.y;
  }
  if (tid < CHT) {  // cls-token passthrough
    size_t idx = (size_t)b * NTOKP * NC + c0 + tid;
    out[idx] = x[idx];
  }
  // fused MLP finalize: sum 12 tile partials -> gelu -> layer 2 -> m2s
  if (tid < NHID) {
    float a = b1[tid];
#pragma unroll
    for (int s = 0; s < NTILE; ++s)
      a += __half2float(partial[((size_t)b * NTILE + s) * NHID + tid]);
    float ge = 0.5f * a * (1.f + erff(a * 0.70710678118654752f));  // exact gelu
    sh2[tid] = make_float2(ge * w2[2 * tid], ge * w2[2 * tid + 1]);
  }
  __syncthreads();
  if (tid < 64) {
    float p0 = sh2[tid].x + sh2[tid + 64].x + sh2[tid + 128].x;
    float p1 = sh2[tid].y + sh2[tid + 64].y + sh2[tid + 128].y;
#pragma unroll
    for (int off = 32; off; off >>= 1) {
      p0 += __shfl_down(p0, off);
      p1 += __shfl_down(p1, off);
    }
    if (tid == 0) {
      float o0 = p0 + b2[0], o1 = p1 + b2[1];
      float muv = fmaxf(9.899494936611665f / (1.f + expf(-o0)), 1.f);
      float sp = (o1 > 20.f) ? o1 : log1pf(expf(o1));
      float sg = fmaxf(sp, 0.1f);
      msb_sh = 2.f * muv * muv * sg + 1e-6f;
    }
  }
  __syncthreads();
  float msb = msb_sh;
  if (tid < NH) {
    int f = (tid <= 7) ? tid : 14 - tid;
    wexp[tid] = __expf(-(float)(f * f) / msb);
  }
  __syncthreads();
  if (tid < NH) {
    float s = 0.f;
#pragma unroll
    for (int k = 0; k < NH; ++k) s = fmaf(wexp[k], CT14[(k * tid) % 14], s);
    kc[tid] = s * (1.f / 14.f);
  }
  float g = gamma[c0 + c], be = beta[c0 + c];
  float rg = 1.f / g;
  __syncthreads();

  float kr[NH];
#pragma unroll
  for (int d = 0; d < NH; ++d) kr[d] = kc[d];
  // packed kernel-pair table: khp[d] = {kr[d], kr[(d+1)%14]}
  __half2 khp[NH];
#pragma unroll
  for (int d = 0; d < NH; ++d) khp[d] = __floats2half2_rn(kr[d], kr[(d + 1) % 14]);

  // stage 1: per (c,i): {y0,y1}[jp] = sum_j xn[i,j] * {kr[(2jp-j)%14], kr[(2jp+1-j)%14]}
#pragma unroll 1
  for (int i = w; i < NH; i += 4) {
    __half2 xh[NH];
    if (UH) {
      const __half* xr = xnh + ((size_t)b * NTOK + i * NH) * NC + c0 + c;
#pragma unroll
      for (int j = 0; j < NH; ++j) xh[j] = __half2half2(xr[(size_t)j * NC]);
    } else {
      const float* xr = x + ((size_t)b * NTOKP + 1 + i * NH) * NC + c0 + c;
#pragma unroll
      for (int j = 0; j < NH; ++j) {
        float2 m = ms[i * NH + j];
        xh[j] = __float2half2_rn((xr[(size_t)j * NC] - m.x) * m.y * g + be);
      }
    }
#pragma unroll
    for (int jp = 0; jp < 7; ++jp) {
      __half2 acc = __floats2half2_rn(0.f, 0.f);
#pragma unroll
      for (int j = 0; j < NH; ++j)
        acc = __hfma2(xh[j], khp[(2 * jp - j + 28) % 14], acc);
      T[(i * 7 + jp) * CHT + c] = acc;
    }
  }
  __syncthreads();

  // stage 2: per (c,jq): {z[2d],z[2d+1]} = sum_i y[i,jq] * khp[(2d-i)%14]
#pragma unroll 1
  for (int jq = w; jq < NH; jq += 4) {
    int jp = jq >> 1, hi = jq & 1;
    __half2 acc2[7];
#pragma unroll
    for (int d = 0; d < 7; ++d) acc2[d] = __floats2half2_rn(0.f, 0.f);
#pragma unroll
    for (int i = 0; i < NH; ++i) {
      __half2 t = T[(i * 7 + jp) * CHT + c];
      __half2 yi = hi ? __high2half2(t) : __low2half2(t);  // wave-uniform select
#pragma unroll
      for (int d = 0; d < 7; ++d)
        acc2[d] = __hfma2(yi, khp[(2 * d - i + 28) % 14], acc2[d]);
    }
    float* outr = out + ((size_t)b * NTOKP + 1 + jq) * NC + c0 + c;
    const __half* xq = xnh + ((size_t)b * NTOK + jq) * NC + c0 + c;
    const float* xr = x + ((size_t)b * NTOKP + 1 + jq) * NC + c0 + c;
#pragma unroll
    for (int ii = 0; ii < NH; ++ii) {
      float z = (ii & 1) ? __high2float(acc2[ii >> 1]) : __low2float(acc2[ii >> 1]);
      if (UH) {
        float xnv = __half2float(xq[(size_t)ii * NH * NC]);
        int t = ii * NH + jq;
        float xv = fmaf((xnv - be) * rg, rr[t], ms[t].x);
        outr[(size_t)ii * NH * NC] = xv + rs * (z - xnv);
      } else {
        float xv = xr[(size_t)ii * NH * NC];
        float2 m = ms[ii * NH + jq];
        float xn = (xv - m.x) * m.y * g + be;
        outr[(size_t)ii * NH * NC] = xv + rs * (z - xn);
      }
    }
  }
}

extern "C" void kernel_launch(void* const* d_in, const int* in_sizes, int n_in,
                              void* d_out, int out_size, void* d_ws, size_t ws_size,
                              hipStream_t stream) {
  (void)in_sizes; (void)n_in; (void)out_size;
  const float* x      = (const float*)d_in[0];
  const float* gamma  = (const float*)d_in[1];
  const float* beta   = (const float*)d_in[2];
  const float* w1     = (const float*)d_in[3];
  const float* b1     = (const float*)d_in[4];
  const float* w2     = (const float*)d_in[5];
  const float* b2     = (const float*)d_in[6];
  const float* rscale = (const float*)d_in[7];
  float* out = (float*)d_out;

  char* wsb = (char*)d_ws;
  float2* msv     = (float2*)(wsb + 0);        //   401,408 B
  __half* partial = (__half*)(wsb + 401408);   // 1,179,648 B  [NB][NTILE][NHID]
  __half* xnh     = (__half*)(wsb + 1581056);  // 77,070,336 B
  size_t need = 1581056 + (size_t)NB * NTOK * NC * 2;  // 78.65 MB
  bool useH = ws_size >= need;

  if (useH) {
    k_stats<true><<<NB * NTOK / 4, 256, 0, stream>>>(x, gamma, beta, msv, xnh);
    k_fwd<true><<<dim3(NTILE, NB), 256, 0, stream>>>(x, xnh, gamma, beta, msv,
                                                     w1, partial);
    k_inv<true><<<dim3(NTILE, NB), 256, 0, stream>>>(x, xnh, gamma, beta, msv,
                                                     partial, b1, w2, b2,
                                                     rscale, out);
  } else {
    k_stats<false><<<NB * NTOK / 4, 256, 0, stream>>>(x, gamma, beta, msv, xnh);
    k_fwd<false><<<dim3(NTILE, NB), 256, 0, stream>>>(x, xnh, gamma, beta, msv,
                                                      w1, partial);
    k_inv<false><<<dim3(NTILE, NB), 256, 0, stream>>>(x, xnh, gamma, beta, msv,
                                                      partial, b1, w2, b2,
                                                      rscale, out);
  }
}